// Round 9
// baseline (384.003 us; speedup 1.0000x reference)
//
#include <hip/hip_runtime.h>

typedef __attribute__((ext_vector_type(8))) short short8;
typedef __attribute__((ext_vector_type(4))) float f32x4;
typedef __attribute__((ext_vector_type(4))) unsigned uint4v;

__device__ __forceinline__ void gload_lds16(const void* g, void* l) {
    __builtin_amdgcn_global_load_lds(
        (const __attribute__((address_space(1))) unsigned*)g,
        (__attribute__((address_space(3))) unsigned*)l, 16, 0, 0);
}
#define MFMA16(a, b, c) __builtin_amdgcn_mfma_f32_16x16x32_bf16((a), (b), (c), 0, 0, 0)

// ---------------------------------------------------------------------------
// fp32 GEMM (R7-verified): BM=32 BN=32 BK=32, 256 thr, 1x4 microtile.
// Used ONLY for enc1 (+ fused w2 transpose/split side-job on blockIdx.y>=32).
// ---------------------------------------------------------------------------
template<bool RELU, bool SPLITW2>
__global__ __launch_bounds__(256)
void gemm_s(const float* __restrict__ A,
            const float* __restrict__ B0, const float* __restrict__ bias0,
            float* __restrict__ C0,
            int M, int N, int K,
            const float* __restrict__ w2, short* __restrict__ w2th,
            short* __restrict__ w2tl)
{
    if (SPLITW2 && blockIdx.y >= 32) {
        int e = ((blockIdx.y - 32) * gridDim.x + blockIdx.x) * 256 + threadIdx.x;
        if (e < 32768) {
            int k = e >> 7, n = e & 127;
            float x = w2[e];
            unsigned hu = __float_as_uint(x) & 0xFFFF0000u;
            w2th[n * 256 + k] = (short)(hu >> 16);
            w2tl[n * 256 + k] = (short)(__float_as_uint(x - __uint_as_float(hu)) >> 16);
        }
        return;
    }
    const float* B = B0; const float* bias = bias0; float* C = C0;
    const int m0 = blockIdx.y * 32, n0 = blockIdx.x * 32;
    const int tid = threadIdx.x;
    const int tx = tid & 7, ty = tid >> 3;

    __shared__ __align__(16) float As[32 * 36];
    __shared__ __align__(16) float Bs[32 * 36];

    float acc[4] = {};
    for (int k0 = 0; k0 < K; k0 += 32) {
        {
            int row = ty, kq = tx << 2;
            float4 v = *(const float4*)&A[(long)(m0 + row) * K + k0 + kq];
            As[(kq + 0) * 36 + row] = v.x; As[(kq + 1) * 36 + row] = v.y;
            As[(kq + 2) * 36 + row] = v.z; As[(kq + 3) * 36 + row] = v.w;
        }
        *(float4*)&Bs[ty * 36 + tx * 4] =
            *(const float4*)&B[(long)(k0 + ty) * N + n0 + tx * 4];
        __syncthreads();
#pragma unroll
        for (int k = 0; k < 32; ++k) {
            float a = As[k * 36 + ty];
            float4 b4 = *(const float4*)&Bs[k * 36 + tx * 4];
            acc[0] += a * b4.x; acc[1] += a * b4.y;
            acc[2] += a * b4.z; acc[3] += a * b4.w;
        }
        __syncthreads();
    }

    int m = m0 + ty;
#pragma unroll
    for (int j = 0; j < 4; ++j) {
        int n = n0 + tx * 4 + j;
        float v = acc[j];
        if (bias) v += bias[n];
        if (RELU) v = fmaxf(v, 0.f);
        C[(long)m * N + n] = v;
    }
}

// ---------------------------------------------------------------------------
// enc2_fuse v2: per block 4 complete rows, 8-deep register prefetch.
//   xe = h1 @ ew2 + eb2   (K=512);  eg0 = xe @ we0 + be0   (K=256)
// ---------------------------------------------------------------------------
__global__ __launch_bounds__(256)
void enc2_fuse(const float* __restrict__ h1, const float* __restrict__ ew2,
               const float* __restrict__ eb2, const float* __restrict__ we0,
               const float* __restrict__ be0, float* __restrict__ xe,
               float* __restrict__ eg0)
{
    const int tid = threadIdx.x;
    const int gr0 = blockIdx.x * 4;
    const int r = tid >> 6, cg = (tid & 63) * 4;
    __shared__ __align__(16) float hs[4][512];
    __shared__ __align__(16) float xs[4][256];
    {
        int k0 = (tid & 63) * 8;
        *(float4*)&hs[r][k0]     = *(const float4*)&h1[(long)(gr0 + r) * 512 + k0];
        *(float4*)&hs[r][k0 + 4] = *(const float4*)&h1[(long)(gr0 + r) * 512 + k0 + 4];
    }
    __syncthreads();

    float4 o = {0.f, 0.f, 0.f, 0.f};
    {
        float4 bW[8];
#pragma unroll
        for (int q = 0; q < 8; ++q)
            bW[q] = *(const float4*)&ew2[(long)q * 256 + cg];
        for (int k0 = 0; k0 < 512; k0 += 8) {
#pragma unroll
            for (int q = 0; q < 8; ++q) {
                float4 w = bW[q];
                if (k0 < 504)
                    bW[q] = *(const float4*)&ew2[(long)(k0 + 8 + q) * 256 + cg];
                float a = hs[r][k0 + q];
                o.x += a * w.x; o.y += a * w.y; o.z += a * w.z; o.w += a * w.w;
            }
        }
    }
    float4 bv = *(const float4*)&eb2[cg];
    o.x += bv.x; o.y += bv.y; o.z += bv.z; o.w += bv.w;
    *(float4*)&xs[r][cg] = o;
    *(float4*)&xe[(long)(gr0 + r) * 256 + cg] = o;
    __syncthreads();

    float4 e = {0.f, 0.f, 0.f, 0.f};
    {
        float4 bW[8];
#pragma unroll
        for (int q = 0; q < 8; ++q)
            bW[q] = *(const float4*)&we0[(long)q * 256 + cg];
        for (int k0 = 0; k0 < 256; k0 += 8) {
#pragma unroll
            for (int q = 0; q < 8; ++q) {
                float4 w = bW[q];
                if (k0 < 248)
                    bW[q] = *(const float4*)&we0[(long)(k0 + 8 + q) * 256 + cg];
                float a = xs[r][k0 + q];
                e.x += a * w.x; e.y += a * w.y; e.z += a * w.z; e.w += a * w.w;
            }
        }
    }
    float4 be = *(const float4*)&be0[cg];
    e.x += be.x; e.y += be.y; e.z += be.z; e.w += be.w;
    *(float4*)&eg0[(long)(gr0 + r) * 256 + cg] = e;
}

// ---------------------------------------------------------------------------
// layer_fuse v2: per block 4 complete rows; all GEMM phases use 8-deep
// register prefetch (16 float4 loads in flight) to hide L2 latency at
// 1 wave/SIMD occupancy.
//   ng = bp @ eg_in; sf = h_in @ Ws + bs; x = relu(sf+ng);
//   per-row LN via wave shfl; h' -> LDS (+h_out);
//   !LAST: out0 = h' @ Wn0 + bn0;  LAST: out0 = h'@Wn0, out1 = h'@Wn1.
// ---------------------------------------------------------------------------
template<bool LAST>
__global__ __launch_bounds__(256)
void layer_fuse(const float* __restrict__ h_in, const float* __restrict__ bp,
                const float* __restrict__ eg_in,
                const float* __restrict__ Ws, const float* __restrict__ bs,
                const float* __restrict__ lg, const float* __restrict__ lb,
                const float* __restrict__ Wn0, const float* __restrict__ bn0,
                const float* __restrict__ Wn1,
                float* __restrict__ h_out, float* __restrict__ out0,
                float* __restrict__ out1)
{
    const int tid = threadIdx.x;
    const int gr0 = blockIdx.x * 4;
    const int b = gr0 >> 8;
    const float* egb = eg_in + (long)b * 65536;
    const int r = tid >> 6, cg = (tid & 63) * 4;
    __shared__ __align__(16) float hs[4][256];
    __shared__ __align__(16) float ps[4][256];
    {
        int k0 = (tid & 63) * 4;
        *(float4*)&hs[r][k0] = *(const float4*)&h_in[(long)(gr0 + r) * 256 + k0];
        *(float4*)&ps[r][k0] = *(const float4*)&bp[(long)(gr0 + r) * 256 + k0];
    }
    __syncthreads();

    // Phase 1: dual GEMM (ng from eg, sf from Ws), 8-deep prefetch
    float4 ng = {0.f, 0.f, 0.f, 0.f}, sf = {0.f, 0.f, 0.f, 0.f};
    {
        float4 bE[8], bW[8];
#pragma unroll
        for (int q = 0; q < 8; ++q) {
            bE[q] = *(const float4*)&egb[(long)q * 256 + cg];
            bW[q] = *(const float4*)&Ws[(long)q * 256 + cg];
        }
        for (int k0 = 0; k0 < 256; k0 += 8) {
#pragma unroll
            for (int q = 0; q < 8; ++q) {
                float4 we = bE[q], ws = bW[q];
                if (k0 < 248) {
                    bE[q] = *(const float4*)&egb[(long)(k0 + 8 + q) * 256 + cg];
                    bW[q] = *(const float4*)&Ws[(long)(k0 + 8 + q) * 256 + cg];
                }
                float ap = ps[r][k0 + q];
                float ah = hs[r][k0 + q];
                ng.x += ap * we.x; ng.y += ap * we.y;
                ng.z += ap * we.z; ng.w += ap * we.w;
                sf.x += ah * ws.x; sf.y += ah * ws.y;
                sf.z += ah * ws.z; sf.w += ah * ws.w;
            }
        }
    }
    float4 bsv = *(const float4*)&bs[cg];
    float x0 = fmaxf(sf.x + bsv.x + ng.x, 0.f);
    float x1 = fmaxf(sf.y + bsv.y + ng.y, 0.f);
    float x2 = fmaxf(sf.z + bsv.z + ng.z, 0.f);
    float x3 = fmaxf(sf.w + bsv.w + ng.w, 0.f);

    // per-row LN stats: wave r holds the entire row
    float s = x0 + x1 + x2 + x3;
    float s2 = x0 * x0 + x1 * x1 + x2 * x2 + x3 * x3;
#pragma unroll
    for (int off = 1; off < 64; off <<= 1) {
        s  += __shfl_xor(s,  off, 64);
        s2 += __shfl_xor(s2, off, 64);
    }
    const float mu  = s * (1.f / 256.f);
    const float var = s2 * (1.f / 256.f) - mu * mu;
    const float rsv = rsqrtf(var + 1e-5f);
    float4 gv = *(const float4*)&lg[cg];
    float4 bbv = *(const float4*)&lb[cg];
    float4 xl;
    xl.x = (x0 - mu) * rsv * gv.x + bbv.x;
    xl.y = (x1 - mu) * rsv * gv.y + bbv.y;
    xl.z = (x2 - mu) * rsv * gv.z + bbv.z;
    xl.w = (x3 - mu) * rsv * gv.w + bbv.w;

    __syncthreads();               // all hs/ps reads complete
    *(float4*)&hs[r][cg] = xl;     // republish h' in LDS
    if (!LAST)
        *(float4*)&h_out[(long)(gr0 + r) * 256 + cg] = xl;
    __syncthreads();

    // Phase 3: next GEMM(s), 8-deep prefetch
    {
        float4 a0 = {0.f, 0.f, 0.f, 0.f};
        float4 bW[8];
#pragma unroll
        for (int q = 0; q < 8; ++q)
            bW[q] = *(const float4*)&Wn0[(long)q * 256 + cg];
        for (int k0 = 0; k0 < 256; k0 += 8) {
#pragma unroll
            for (int q = 0; q < 8; ++q) {
                float4 w = bW[q];
                if (k0 < 248)
                    bW[q] = *(const float4*)&Wn0[(long)(k0 + 8 + q) * 256 + cg];
                float a = hs[r][k0 + q];
                a0.x += a * w.x; a0.y += a * w.y; a0.z += a * w.z; a0.w += a * w.w;
            }
        }
        if (!LAST) {
            float4 bn = *(const float4*)&bn0[cg];
            a0.x += bn.x; a0.y += bn.y; a0.z += bn.z; a0.w += bn.w;
            *(float4*)&out0[(long)(gr0 + r) * 256 + cg] = a0;
        } else {
            *(float4*)&out0[(long)(gr0 + r) * 256 + cg] = a0;   // hi (no bias)
        }
    }
    if (LAST) {
        float4 a1 = {0.f, 0.f, 0.f, 0.f};
        float4 bW[8];
#pragma unroll
        for (int q = 0; q < 8; ++q)
            bW[q] = *(const float4*)&Wn1[(long)q * 256 + cg];
        for (int k0 = 0; k0 < 256; k0 += 8) {
#pragma unroll
            for (int q = 0; q < 8; ++q) {
                float4 w = bW[q];
                if (k0 < 248)
                    bW[q] = *(const float4*)&Wn1[(long)(k0 + 8 + q) * 256 + cg];
                float a = hs[r][k0 + q];
                a1.x += a * w.x; a1.y += a * w.y; a1.z += a * w.z; a1.w += a * w.w;
            }
        }
        *(float4*)&out1[(long)(gr0 + r) * 256 + cg] = a1;       // hj (no bias)
    }
}

// ---------------------------------------------------------------------------
// Pairwise scorer v4 (R7-verified, byte-identical): all-b128 LDS traffic,
// double-buffered P, ONE barrier per k-tile, MFMA bf16 3-pass hi/lo.
// ---------------------------------------------------------------------------
#define STAGE_HJ(T, BUF)                                                        \
    {                                                                           \
        int row = tid >> 3, s = tid & 7;                                        \
        gload_lds16(&hja[((long)(b * 256 + j0 + row)) * 256 + (T) * 32          \
                         + ((s ^ (row & 7)) << 2)],                             \
                    (char*)&hjs[BUF][0] + tid * 16);                            \
        int row2 = row + 32;                                                    \
        gload_lds16(&hja[((long)(b * 256 + j0 + row2)) * 256 + (T) * 32         \
                         + ((s ^ (row2 & 7)) << 2)],                            \
                    (char*)&hjs[BUF][0] + 4096 + tid * 16);                     \
    }

#define BUILD_P(KT, BUF)                                                        \
    {                                                                           \
        const char* hbase = (const char*)&hjs[BUF][0] + jj * 128;               \
        char* phc = (char*)&Ph[BUF][0];                                         \
        char* plc = (char*)&Pl[BUF][0];                                         \
        const int swz = (p & 7) << 4;                                           \
        _Pragma("unroll")                                                       \
        for (int q = 0; q < 2; ++q) {                                           \
            const int oct = o0 + q;                                             \
            float4 hv0 = *(const float4*)(hbase + (((oct * 2)     ^ (jj & 7)) << 4)); \
            float4 hv1 = *(const float4*)(hbase + (((oct * 2 + 1) ^ (jj & 7)) << 4)); \
            float4 iv0 = *(const float4*)&hib[ii][(KT) * 32 + oct * 8];         \
            float4 iv1 = *(const float4*)&hib[ii][(KT) * 32 + oct * 8 + 4];     \
            float4 cv0 = *(const float4*)&csv[(KT) * 32 + oct * 8];             \
            float4 cv1 = *(const float4*)&csv[(KT) * 32 + oct * 8 + 4];         \
            float x0 = fmaxf(fmaf(bpw, cv0.x, iv0.x) + hv0.x, 0.f);             \
            float x1 = fmaxf(fmaf(bpw, cv0.y, iv0.y) + hv0.y, 0.f);             \
            float x2 = fmaxf(fmaf(bpw, cv0.z, iv0.z) + hv0.z, 0.f);             \
            float x3 = fmaxf(fmaf(bpw, cv0.w, iv0.w) + hv0.w, 0.f);             \
            float x4 = fmaxf(fmaf(bpw, cv1.x, iv1.x) + hv1.x, 0.f);             \
            float x5 = fmaxf(fmaf(bpw, cv1.y, iv1.y) + hv1.y, 0.f);             \
            float x6 = fmaxf(fmaf(bpw, cv1.z, iv1.z) + hv1.z, 0.f);             \
            float x7 = fmaxf(fmaf(bpw, cv1.w, iv1.w) + hv1.w, 0.f);             \
            unsigned h0 = __float_as_uint(x0) & 0xFFFF0000u;                    \
            unsigned h1 = __float_as_uint(x1) & 0xFFFF0000u;                    \
            unsigned h2 = __float_as_uint(x2) & 0xFFFF0000u;                    \
            unsigned h3 = __float_as_uint(x3) & 0xFFFF0000u;                    \
            unsigned h4 = __float_as_uint(x4) & 0xFFFF0000u;                    \
            unsigned h5 = __float_as_uint(x5) & 0xFFFF0000u;                    \
            unsigned h6 = __float_as_uint(x6) & 0xFFFF0000u;                    \
            unsigned h7 = __float_as_uint(x7) & 0xFFFF0000u;                    \
            uint4v hv_, lv_;                                                    \
            hv_[0] = (h0 >> 16) | h1;                                           \
            hv_[1] = (h2 >> 16) | h3;                                           \
            hv_[2] = (h4 >> 16) | h5;                                           \
            hv_[3] = (h6 >> 16) | h7;                                           \
            lv_[0] = (__float_as_uint(x0 - __uint_as_float(h0)) >> 16)          \
                   | (__float_as_uint(x1 - __uint_as_float(h1)) & 0xFFFF0000u); \
            lv_[1] = (__float_as_uint(x2 - __uint_as_float(h2)) >> 16)          \
                   | (__float_as_uint(x3 - __uint_as_float(h3)) & 0xFFFF0000u); \
            lv_[2] = (__float_as_uint(x4 - __uint_as_float(h4)) >> 16)          \
                   | (__float_as_uint(x5 - __uint_as_float(h5)) & 0xFFFF0000u); \
            lv_[3] = (__float_as_uint(x6 - __uint_as_float(h6)) >> 16)          \
                   | (__float_as_uint(x7 - __uint_as_float(h7)) & 0xFFFF0000u); \
            int sbyte = p * 64 + oct * 16;                                      \
            *(uint4v*)(phc + (sbyte ^ swz)) = hv_;                              \
            *(uint4v*)(plc + (sbyte ^ swz)) = lv_;                              \
        }                                                                       \
    }

__global__ __launch_bounds__(256, 3)
void pairwise4(const float* __restrict__ hia, const float* __restrict__ hja,
               const float* __restrict__ bpm,
               const float* __restrict__ c, const float* __restrict__ b1,
               const short* __restrict__ w2th, const short* __restrict__ w2tl,
               const float* __restrict__ b2, const float* __restrict__ w3,
               const float* __restrict__ b3, float* __restrict__ out)
{
    const int b = blockIdx.z, ib0 = blockIdx.y * 2, j0 = blockIdx.x * 64;
    const int tid = threadIdx.x, l = tid & 63, wid = tid >> 6;
    const int wm0 = (wid & 1) * 64, wn0 = (wid >> 1) * 64;
    const int g = l >> 4, ln = l & 15;
    const int p = tid >> 1, jj = p & 63, ii = p >> 6, o0 = (tid & 1) * 2;

    __shared__ __align__(16) short Ph[2][4096];
    __shared__ __align__(16) short Pl[2][4096];
    __shared__ __align__(16) float hjs[2][2048];
    __shared__ __align__(16) float hib[2][256];
    __shared__ __align__(16) float csv[256];
    __shared__ float bpv[128];
    __shared__ float red[128][2];

    if (tid < 128)
        bpv[tid] = bpm[((long)(b * 256 + ib0 + (tid >> 6))) * 256 + j0 + (tid & 63)];
    {
        int i2 = tid >> 7, kk = (tid & 127) * 2;
        float2 hv = *(const float2*)&hia[((long)(b * 256 + ib0 + i2)) * 256 + kk];
        float2 bv = *(const float2*)&b1[kk];
        hib[i2][kk] = hv.x + bv.x; hib[i2][kk + 1] = hv.y + bv.y;
    }
    if (tid < 64) *(float4*)&csv[tid * 4] = *(const float4*)&c[tid * 4];

    STAGE_HJ(0, 0);
    __syncthreads();
    const float bpw = bpv[p];
    STAGE_HJ(1, 1);
    BUILD_P(0, 0);
    __syncthreads();

    f32x4 acc[4][4] = {};

#pragma unroll
    for (int kt = 0; kt < 8; ++kt) {
        const int cur = kt & 1;
        if (kt < 6) STAGE_HJ(kt + 2, cur);
        short8 bh[4], bl[4];
#pragma unroll
        for (int nf = 0; nf < 4; ++nf) {
            int col = wn0 + nf * 16 + ln;
            long bo = (long)col * 256 + kt * 32 + g * 8;
            bh[nf] = *(const short8*)(w2th + bo);
            bl[nf] = *(const short8*)(w2tl + bo);
        }
        if (kt < 7) BUILD_P(kt + 1, cur ^ 1);
        short8 ah[4], al[4];
#pragma unroll
        for (int mf = 0; mf < 4; ++mf) {
            int row = wm0 + mf * 16 + ln;
            int off = (row * 64 + g * 16) ^ ((row & 7) << 4);
            ah[mf] = *(const short8*)((const char*)&Ph[cur][0] + off);
            al[mf] = *(const short8*)((const char*)&Pl[cur][0] + off);
        }
#pragma unroll
        for (int mf = 0; mf < 4; ++mf)
#pragma unroll
            for (int nf = 0; nf < 4; ++nf) {
                acc[mf][nf] = MFMA16(ah[mf], bh[nf], acc[mf][nf]);
                acc[mf][nf] = MFMA16(ah[mf], bl[nf], acc[mf][nf]);
                acc[mf][nf] = MFMA16(al[mf], bh[nf], acc[mf][nf]);
            }
        __syncthreads();
    }

    float b2v[4], w3v[4];
#pragma unroll
    for (int nf = 0; nf < 4; ++nf) {
        int col = wn0 + nf * 16 + ln;
        b2v[nf] = b2[col];
        w3v[nf] = w3[col];
    }
#pragma unroll
    for (int mf = 0; mf < 4; ++mf) {
#pragma unroll
        for (int r = 0; r < 4; ++r) {
            float s = 0.f;
#pragma unroll
            for (int nf = 0; nf < 4; ++nf)
                s += fmaxf(acc[mf][nf][r] + b2v[nf], 0.f) * w3v[nf];
            s += __shfl_xor(s, 1, 64);
            s += __shfl_xor(s, 2, 64);
            s += __shfl_xor(s, 4, 64);
            s += __shfl_xor(s, 8, 64);
            if (ln == 0)
                red[wm0 + mf * 16 + g * 4 + r][wid >> 1] = s;
        }
    }
    __syncthreads();
    if (tid < 128) {
        int i = ib0 + (tid >> 6), j = j0 + (tid & 63);
        out[((long)(b * 256 + i)) * 256 + j] = red[tid][0] + red[tid][1] + b3[0];
    }
}

// ---------------------------------------------------------------------------
extern "C" void kernel_launch(void* const* d_in, const int* in_sizes, int n_in,
                              void* d_out, int out_size, void* d_ws, size_t ws_size,
                              hipStream_t stream)
{
    const float* emb   = (const float*)d_in[0];
    const float* bp    = (const float*)d_in[1];
    const float* ew1   = (const float*)d_in[3];
    const float* eb1   = (const float*)d_in[4];
    const float* ew2   = (const float*)d_in[5];
    const float* eb2   = (const float*)d_in[6];
    const float* wself = (const float*)d_in[7];
    const float* bself = (const float*)d_in[8];
    const float* wedge = (const float*)d_in[9];
    const float* bedge = (const float*)d_in[10];
    const float* lng   = (const float*)d_in[11];
    const float* lnb   = (const float*)d_in[12];
    const float* mw1   = (const float*)d_in[13];
    const float* mb1   = (const float*)d_in[14];
    const float* mw2   = (const float*)d_in[15];
    const float* mb2   = (const float*)d_in[16];
    const float* mw3   = (const float*)d_in[17];
    const float* mb3   = (const float*)d_in[18];
    float* out = (float*)d_out;

    float* ws = (float*)d_ws;
    float* h1  = ws;               // 524288 (enc hidden)
    float* hA  = h1 + 524288;      // 262144
    float* hB  = hA + 262144;      // 262144
    float* egA = hB + 262144;      // 262144
    float* egB = egA + 262144;     // 262144
    float* hi  = egB + 262144;     // 262144
    float* hj  = hi + 262144;      // 262144
    short* w2th = (short*)(hj + 262144);   // 32768 shorts
    short* w2tl = w2th + 32768;            // 32768 shorts

    dim3 blk(256);

    // 1. enc1 (tiled, relu) + w2 transpose/split side-job
    gemm_s<true, true><<<dim3(16, 40), blk, 0, stream>>>(emb, ew1, eb1, h1,
        1024, 512, 640, mw2, w2th, w2tl);

    // 2. enc2 + eg0
    enc2_fuse<<<dim3(256), blk, 0, stream>>>(h1, ew2, eb2, wedge, bedge, hA, egA);

    // 3-5. GCN layers, each one dispatch
    layer_fuse<false><<<dim3(256), blk, 0, stream>>>(hA, bp, egA,
        wself, bself, lng, lnb,
        wedge + 65536, bedge + 256, nullptr, hB, egB, nullptr);
    layer_fuse<false><<<dim3(256), blk, 0, stream>>>(hB, bp, egB,
        wself + 65536, bself + 256, lng + 256, lnb + 256,
        wedge + 131072, bedge + 512, nullptr, hA, egA, nullptr);
    layer_fuse<true><<<dim3(256), blk, 0, stream>>>(hA, bp, egA,
        wself + 131072, bself + 512, lng + 512, lnb + 512,
        mw1, nullptr, mw1 + 65536, hB, hi, hj);

    // 6. pairwise MFMA scorer
    pairwise4<<<dim3(4, 128, 4), blk, 0, stream>>>(hi, hj, bp,
        mw1 + 131072, mb1, w2th, w2tl, mb2, mw3, mb3, out);
}

// Round 10
// 356.200 us; speedup vs baseline: 1.0781x; 1.0781x over previous
//
#include <hip/hip_runtime.h>

typedef __attribute__((ext_vector_type(8))) short short8;
typedef __attribute__((ext_vector_type(4))) float f32x4;
typedef __attribute__((ext_vector_type(4))) unsigned uint4v;

#define MFMA16(a, b, c) __builtin_amdgcn_mfma_f32_16x16x32_bf16((a), (b), (c), 0, 0, 0)

// ---------------------------------------------------------------------------
// fp32 GEMM (R7-verified, verbatim): BM=32 BN=32 BK=32, 256 thr, 1x4 micro.
// Dual-B via nxHalf. Optional LN-on-A-load (stats from ps[4][1024][2]).
// Optional fused w2-split side-job on blocks with blockIdx.y >= 32.
// ---------------------------------------------------------------------------
template<bool RELU, bool LNA, bool SPLITW2>
__global__ __launch_bounds__(256)
void gemm_s(const float* __restrict__ A,
            const float* __restrict__ B0, const float* __restrict__ bias0,
            float* __restrict__ C0,
            const float* __restrict__ B1, const float* __restrict__ bias1,
            float* __restrict__ C1,
            const float* __restrict__ ps, const float* __restrict__ lg,
            const float* __restrict__ lb,
            int M, int N, int K, int nxHalf,
            const float* __restrict__ w2, short* __restrict__ w2th,
            short* __restrict__ w2tl)
{
    if (SPLITW2 && blockIdx.y >= 32) {
        int e = ((blockIdx.y - 32) * gridDim.x + blockIdx.x) * 256 + threadIdx.x;
        if (e < 32768) {
            int k = e >> 7, n = e & 127;
            float x = w2[e];
            unsigned hu = __float_as_uint(x) & 0xFFFF0000u;
            w2th[n * 256 + k] = (short)(hu >> 16);
            w2tl[n * 256 + k] = (short)(__float_as_uint(x - __uint_as_float(hu)) >> 16);
        }
        return;
    }
    int bx = blockIdx.x;
    const float* B = B0; const float* bias = bias0; float* C = C0;
    if (nxHalf && bx >= nxHalf) { bx -= nxHalf; B = B1; bias = bias1; C = C1; }
    const int m0 = blockIdx.y * 32, n0 = bx * 32;
    const int tid = threadIdx.x;
    const int tx = tid & 7, ty = tid >> 3;

    __shared__ __align__(16) float As[32 * 36];
    __shared__ __align__(16) float Bs[32 * 36];
    __shared__ float mus[32], rss[32];

    if (LNA) {
        if (tid < 32) {
            int m = m0 + tid;
            float s  = ps[m * 2]            + ps[2048 + m * 2]
                     + ps[4096 + m * 2]     + ps[6144 + m * 2];
            float s2 = ps[m * 2 + 1]        + ps[2048 + m * 2 + 1]
                     + ps[4096 + m * 2 + 1] + ps[6144 + m * 2 + 1];
            float mu  = s * (1.f / 256.f);
            float var = s2 * (1.f / 256.f) - mu * mu;
            mus[tid] = mu;
            rss[tid] = rsqrtf(var + 1e-5f);
        }
        __syncthreads();
    }

    float acc[4] = {};
    for (int k0 = 0; k0 < K; k0 += 32) {
        {   // A tile (transposed to As[k][m]), optional LN
            int row = ty, kq = tx << 2;
            float4 v = *(const float4*)&A[(long)(m0 + row) * K + k0 + kq];
            if (LNA) {
                float4 gv = *(const float4*)&lg[k0 + kq];
                float4 bv = *(const float4*)&lb[k0 + kq];
                float mu = mus[row], rs = rss[row];
                v.x = (v.x - mu) * rs * gv.x + bv.x;
                v.y = (v.y - mu) * rs * gv.y + bv.y;
                v.z = (v.z - mu) * rs * gv.z + bv.z;
                v.w = (v.w - mu) * rs * gv.w + bv.w;
            }
            As[(kq + 0) * 36 + row] = v.x; As[(kq + 1) * 36 + row] = v.y;
            As[(kq + 2) * 36 + row] = v.z; As[(kq + 3) * 36 + row] = v.w;
        }
        *(float4*)&Bs[ty * 36 + tx * 4] =
            *(const float4*)&B[(long)(k0 + ty) * N + n0 + tx * 4];
        __syncthreads();
#pragma unroll
        for (int k = 0; k < 32; ++k) {
            float a = As[k * 36 + ty];
            float4 b4 = *(const float4*)&Bs[k * 36 + tx * 4];
            acc[0] += a * b4.x; acc[1] += a * b4.y;
            acc[2] += a * b4.z; acc[3] += a * b4.w;
        }
        __syncthreads();
    }

    int m = m0 + ty;
#pragma unroll
    for (int j = 0; j < 4; ++j) {
        int n = n0 + tx * 4 + j;
        float v = acc[j];
        if (bias) v += bias[n];
        if (RELU) v = fmaxf(v, 0.f);
        C[(long)m * N + n] = v;
    }
}

// ---------------------------------------------------------------------------
// bmm + fused x = relu(sf + bp@eg) + per-row partial LN stats (R5/R7-proven).
// Grid (4 n-tiles, 8 m-tiles, 4 batch). ps layout: [jb][1024][2].
// ---------------------------------------------------------------------------
__global__ __launch_bounds__(256)
void bmm_fuse(const float* __restrict__ bp, const float* __restrict__ eg,
              const float* __restrict__ sf, float* __restrict__ x,
              float* __restrict__ ps)
{
    const int b = blockIdx.z, jb = blockIdx.x;
    const int m0 = blockIdx.y * 32, n0 = jb * 64;
    const float* A = bp + b * 65536;
    const float* B = eg + b * 65536;
    const int tid = threadIdx.x;
    const int tx = tid & 15, ty = tid >> 4;

    __shared__ __align__(16) float As[32 * 36];
    __shared__ __align__(16) float Bs[32 * 68];

    float acc[2][4] = {};
    for (int k0 = 0; k0 < 256; k0 += 32) {
        {
            int row = tid >> 3, kq = (tid & 7) << 2;
            float4 v = *(const float4*)&A[(long)(m0 + row) * 256 + k0 + kq];
            As[(kq + 0) * 36 + row] = v.x; As[(kq + 1) * 36 + row] = v.y;
            As[(kq + 2) * 36 + row] = v.z; As[(kq + 3) * 36 + row] = v.w;
        }
#pragma unroll
        for (int q = 0; q < 2; ++q) {
            int f = tid * 2 + q;
            int kk = f >> 4, nn = (f & 15) << 2;
            *(float4*)&Bs[kk * 68 + nn] = *(const float4*)&B[(long)(k0 + kk) * 256 + n0 + nn];
        }
        __syncthreads();
#pragma unroll
        for (int k = 0; k < 32; ++k) {
            float2 a2 = *(const float2*)&As[k * 36 + ty * 2];
            float4 b4 = *(const float4*)&Bs[k * 68 + tx * 4];
            acc[0][0] += a2.x * b4.x; acc[0][1] += a2.x * b4.y;
            acc[0][2] += a2.x * b4.z; acc[0][3] += a2.x * b4.w;
            acc[1][0] += a2.y * b4.x; acc[1][1] += a2.y * b4.y;
            acc[1][2] += a2.y * b4.z; acc[1][3] += a2.y * b4.w;
        }
        __syncthreads();
    }

#pragma unroll
    for (int i = 0; i < 2; ++i) {
        int gm = b * 256 + m0 + ty * 2 + i;
        float s = 0.f, s2 = 0.f;
#pragma unroll
        for (int j = 0; j < 4; ++j) {
            int n = n0 + tx * 4 + j;
            float v = fmaxf(acc[i][j] + sf[(long)gm * 256 + n], 0.f);
            x[(long)gm * 256 + n] = v;
            s += v; s2 += v * v;
        }
        s  += __shfl_xor(s, 1, 64);  s2 += __shfl_xor(s2, 1, 64);
        s  += __shfl_xor(s, 2, 64);  s2 += __shfl_xor(s2, 2, 64);
        s  += __shfl_xor(s, 4, 64);  s2 += __shfl_xor(s2, 4, 64);
        s  += __shfl_xor(s, 8, 64);  s2 += __shfl_xor(s2, 8, 64);
        if (tx == 0) {
            ps[jb * 2048 + gm * 2]     = s;
            ps[jb * 2048 + gm * 2 + 1] = s2;
        }
    }
}

// ---------------------------------------------------------------------------
// Pairwise scorer v5: P built ENTIRELY IN REGISTERS in MFMA fragment layout.
// No P LDS, no double buffers, NO BARRIERS in the k-loop. Each lane (g,ln)
// of wave (wm0,wn0) computes P[wm0+mf*16+ln][g*8..+7] for mf=0..3 directly:
//   hj slices loaded per-lane from global (L2-hot), hi+b1 / c broadcast from
//   LDS, bp weight per row. 3-pass bf16 hi/lo split -> MFMA, fp32 accumulate.
// Block: 128 pairs (2 i x 64 j) x N=128, 4 waves (2 pair-halves x 2 N-halves).
// ---------------------------------------------------------------------------
__global__ __launch_bounds__(256, 3)
void pairwise5(const float* __restrict__ hia, const float* __restrict__ hja,
               const float* __restrict__ bpm,
               const float* __restrict__ c, const float* __restrict__ b1,
               const short* __restrict__ w2th, const short* __restrict__ w2tl,
               const float* __restrict__ b2, const float* __restrict__ w3,
               const float* __restrict__ b3, float* __restrict__ out)
{
    const int b = blockIdx.z, ib0 = blockIdx.y * 2, j0 = blockIdx.x * 64;
    const int tid = threadIdx.x, l = tid & 63, wid = tid >> 6;
    const int wm0 = (wid & 1) * 64, wn0 = (wid >> 1) * 64;
    const int g = l >> 4, ln = l & 15;
    const int ii = wm0 >> 6;   // which of the 2 i-rows this wave's pairs use

    __shared__ __align__(16) float hib[2][256];   // hi row + b1
    __shared__ __align__(16) float csv[256];      // mlp_w1[512] row
    __shared__ float bpv[128];
    __shared__ float red[128][2];

    if (tid < 128)
        bpv[tid] = bpm[((long)(b * 256 + ib0 + (tid >> 6))) * 256 + j0 + (tid & 63)];
    {
        int i2 = tid >> 7, kk = (tid & 127) * 2;
        float2 hv = *(const float2*)&hia[((long)(b * 256 + ib0 + i2)) * 256 + kk];
        float2 bv = *(const float2*)&b1[kk];
        hib[i2][kk] = hv.x + bv.x; hib[i2][kk + 1] = hv.y + bv.y;
    }
    if (tid < 64) *(float4*)&csv[tid * 4] = *(const float4*)&c[tid * 4];
    __syncthreads();   // only barrier before the epilogue

    float bw[4];
    const float* hjr[4];
#pragma unroll
    for (int mf = 0; mf < 4; ++mf) {
        bw[mf] = bpv[wm0 + mf * 16 + ln];          // pair row wm0+mf*16+ln
        hjr[mf] = &hja[((long)(b * 256 + j0 + mf * 16 + ln)) * 256];
    }

    f32x4 acc[4][4] = {};

#pragma unroll
    for (int kt = 0; kt < 8; ++kt) {
        const int kb = kt * 32 + g * 8;
        // B fragments (w2 splits, 128 KB L2-hot) — issued first
        short8 bh[4], bl[4];
#pragma unroll
        for (int nf = 0; nf < 4; ++nf) {
            long bo = (long)(wn0 + nf * 16 + ln) * 256 + kb;
            bh[nf] = *(const short8*)(w2th + bo);
            bl[nf] = *(const short8*)(w2tl + bo);
        }
        // per-lane hj slices (global, L2-hot) — issued before the build VALU
        float4 hj0[4], hj1[4];
#pragma unroll
        for (int mf = 0; mf < 4; ++mf) {
            hj0[mf] = *(const float4*)(hjr[mf] + kb);
            hj1[mf] = *(const float4*)(hjr[mf] + kb + 4);
        }
        // broadcast slices (LDS, same addr per 16-lane group)
        float4 iv0 = *(const float4*)&hib[ii][kb];
        float4 iv1 = *(const float4*)&hib[ii][kb + 4];
        float4 cv0 = *(const float4*)&csv[kb];
        float4 cv1 = *(const float4*)&csv[kb + 4];

#pragma unroll
        for (int mf = 0; mf < 4; ++mf) {
            float x0 = fmaxf(fmaf(bw[mf], cv0.x, iv0.x) + hj0[mf].x, 0.f);
            float x1 = fmaxf(fmaf(bw[mf], cv0.y, iv0.y) + hj0[mf].y, 0.f);
            float x2 = fmaxf(fmaf(bw[mf], cv0.z, iv0.z) + hj0[mf].z, 0.f);
            float x3 = fmaxf(fmaf(bw[mf], cv0.w, iv0.w) + hj0[mf].w, 0.f);
            float x4 = fmaxf(fmaf(bw[mf], cv1.x, iv1.x) + hj1[mf].x, 0.f);
            float x5 = fmaxf(fmaf(bw[mf], cv1.y, iv1.y) + hj1[mf].y, 0.f);
            float x6 = fmaxf(fmaf(bw[mf], cv1.z, iv1.z) + hj1[mf].z, 0.f);
            float x7 = fmaxf(fmaf(bw[mf], cv1.w, iv1.w) + hj1[mf].w, 0.f);
            unsigned h0 = __float_as_uint(x0) & 0xFFFF0000u;
            unsigned h1 = __float_as_uint(x1) & 0xFFFF0000u;
            unsigned h2 = __float_as_uint(x2) & 0xFFFF0000u;
            unsigned h3 = __float_as_uint(x3) & 0xFFFF0000u;
            unsigned h4 = __float_as_uint(x4) & 0xFFFF0000u;
            unsigned h5 = __float_as_uint(x5) & 0xFFFF0000u;
            unsigned h6 = __float_as_uint(x6) & 0xFFFF0000u;
            unsigned h7 = __float_as_uint(x7) & 0xFFFF0000u;
            union { uint4v u; short8 s; } ua, ul;
            ua.u[0] = (h0 >> 16) | h1;
            ua.u[1] = (h2 >> 16) | h3;
            ua.u[2] = (h4 >> 16) | h5;
            ua.u[3] = (h6 >> 16) | h7;
            ul.u[0] = (__float_as_uint(x0 - __uint_as_float(h0)) >> 16)
                    | (__float_as_uint(x1 - __uint_as_float(h1)) & 0xFFFF0000u);
            ul.u[1] = (__float_as_uint(x2 - __uint_as_float(h2)) >> 16)
                    | (__float_as_uint(x3 - __uint_as_float(h3)) & 0xFFFF0000u);
            ul.u[2] = (__float_as_uint(x4 - __uint_as_float(h4)) >> 16)
                    | (__float_as_uint(x5 - __uint_as_float(h5)) & 0xFFFF0000u);
            ul.u[3] = (__float_as_uint(x6 - __uint_as_float(h6)) >> 16)
                    | (__float_as_uint(x7 - __uint_as_float(h7)) & 0xFFFF0000u);
            short8 ah = ua.s, al = ul.s;
#pragma unroll
            for (int nf = 0; nf < 4; ++nf) {
                acc[mf][nf] = MFMA16(ah, bh[nf], acc[mf][nf]);
                acc[mf][nf] = MFMA16(ah, bl[nf], acc[mf][nf]);
                acc[mf][nf] = MFMA16(al, bh[nf], acc[mf][nf]);
            }
        }
    }

    // epilogue: relu(+b2) dot w3, 16-lane shfl reduce, cross-wave via LDS
    float b2v[4], w3v[4];
#pragma unroll
    for (int nf = 0; nf < 4; ++nf) {
        int col = wn0 + nf * 16 + ln;
        b2v[nf] = b2[col];
        w3v[nf] = w3[col];
    }
#pragma unroll
    for (int mf = 0; mf < 4; ++mf) {
#pragma unroll
        for (int r = 0; r < 4; ++r) {
            float s = 0.f;
#pragma unroll
            for (int nf = 0; nf < 4; ++nf)
                s += fmaxf(acc[mf][nf][r] + b2v[nf], 0.f) * w3v[nf];
            s += __shfl_xor(s, 1, 64);
            s += __shfl_xor(s, 2, 64);
            s += __shfl_xor(s, 4, 64);
            s += __shfl_xor(s, 8, 64);
            if (ln == 0)
                red[wm0 + mf * 16 + g * 4 + r][wid >> 1] = s;
        }
    }
    __syncthreads();
    if (tid < 128) {
        int i = ib0 + (tid >> 6), j = j0 + (tid & 63);
        out[((long)(b * 256 + i)) * 256 + j] = red[tid][0] + red[tid][1] + b3[0];
    }
}

// ---------------------------------------------------------------------------
extern "C" void kernel_launch(void* const* d_in, const int* in_sizes, int n_in,
                              void* d_out, int out_size, void* d_ws, size_t ws_size,
                              hipStream_t stream)
{
    const float* emb   = (const float*)d_in[0];
    const float* bp    = (const float*)d_in[1];
    const float* ew1   = (const float*)d_in[3];
    const float* eb1   = (const float*)d_in[4];
    const float* ew2   = (const float*)d_in[5];
    const float* eb2   = (const float*)d_in[6];
    const float* wself = (const float*)d_in[7];
    const float* bself = (const float*)d_in[8];
    const float* wedge = (const float*)d_in[9];
    const float* bedge = (const float*)d_in[10];
    const float* lng   = (const float*)d_in[11];
    const float* lnb   = (const float*)d_in[12];
    const float* mw1   = (const float*)d_in[13];
    const float* mb1   = (const float*)d_in[14];
    const float* mw2   = (const float*)d_in[15];
    const float* mb2   = (const float*)d_in[16];
    const float* mw3   = (const float*)d_in[17];
    const float* mb3   = (const float*)d_in[18];
    float* out = (float*)d_out;

    float* ws = (float*)d_ws;
    float* h1 = ws;               // 524288  (enc hidden)
    float* xe = h1 + 524288;      // 262144  (enc out)
    float* sf = xe + 262144;      // 262144
    float* eg = sf + 262144;      // 262144
    float* x0 = eg + 262144;      // 262144  (pre-LN layer outs)
    float* x1 = x0 + 262144;
    float* x2 = x1 + 262144;
    float* hi = x2 + 262144;
    float* hj = hi + 262144;
    short* w2th = (short*)(hj + 262144);   // 32768 shorts
    short* w2tl = w2th + 32768;            // 32768 shorts
    float* ps0  = (float*)(w2tl + 32768);  // 3 x [4][1024][2]
    float* ps1  = ps0 + 8192;
    float* ps2  = ps1 + 8192;

    float* xs[3]  = {x0, x1, x2};
    float* pss[3] = {ps0, ps1, ps2};
    dim3 blk(256);

    // FeatureEncoder  (enc1 grid-sliced with the w2 transpose+split side-job)
    gemm_s<true, false, true><<<dim3(16, 40), blk, 0, stream>>>(emb, ew1, eb1, h1,
        nullptr, nullptr, nullptr, nullptr, nullptr, nullptr,
        1024, 512, 640, 0, mw2, w2th, w2tl);
    gemm_s<false, false, false><<<dim3(8, 32), blk, 0, stream>>>(h1, ew2, eb2, xe,
        nullptr, nullptr, nullptr, nullptr, nullptr, nullptr,
        1024, 256, 512, 0, nullptr, nullptr, nullptr);

    // GCN layers: dual self/edge (LN-on-load for l>=1), bmm+relu+stats
    for (int lyr = 0; lyr < 3; ++lyr) {
        const float* Ain = (lyr == 0) ? xe : xs[lyr - 1];
        if (lyr == 0)
            gemm_s<false, false, false><<<dim3(16, 32), blk, 0, stream>>>(Ain,
                wself, bself, sf, wedge, bedge, eg,
                nullptr, nullptr, nullptr, 1024, 256, 256, 8,
                nullptr, nullptr, nullptr);
        else
            gemm_s<false, true, false><<<dim3(16, 32), blk, 0, stream>>>(Ain,
                wself + lyr * 65536, bself + lyr * 256, sf,
                wedge + lyr * 65536, bedge + lyr * 256, eg,
                pss[lyr - 1], lng + (lyr - 1) * 256, lnb + (lyr - 1) * 256,
                1024, 256, 256, 8, nullptr, nullptr, nullptr);
        bmm_fuse<<<dim3(4, 8, 4), blk, 0, stream>>>(bp, eg, sf, xs[lyr], pss[lyr]);
    }

    // hi / hj partial products (dual, LN(x2) applied on A-load)
    gemm_s<false, true, false><<<dim3(16, 32), blk, 0, stream>>>(x2,
        mw1, nullptr, hi, mw1 + 65536, nullptr, hj,
        ps2, lng + 512, lnb + 512, 1024, 256, 256, 8,
        nullptr, nullptr, nullptr);

    // Fused pairwise MFMA scorer (register-built P, barrier-free k-loop)
    pairwise5<<<dim3(4, 128, 4), blk, 0, stream>>>(hi, hj, bp,
        mw1 + 131072, mb1, w2th, w2tl, mb2, mw3, mb3, out);
}